// Round 6
// baseline (1069.362 us; speedup 1.0000x reference)
//
#include <hip/hip_runtime.h>
#include <stdint.h>

#define NODES 60000
#define NPAD  60160   // 235 * 256
#define EDGES 240000
#define KDIM  768
#define HF    768     // HEADS * F_OUT
#define FOUT  128
#define NT    12      // K-tiles of 64

typedef unsigned short u16;
typedef __bf16 bf16x8 __attribute__((ext_vector_type(8)));
typedef float f32x4 __attribute__((ext_vector_type(4)));

__device__ __forceinline__ float bf2f(u16 u) {
  union { uint32_t i; float f; } v; v.i = ((uint32_t)u) << 16; return v.f;
}
__device__ __forceinline__ u16 f2bf(float f) {
  union { float f; uint32_t i; } v; v.f = f;
  return (u16)((v.i + 0x7FFF + ((v.i >> 16) & 1)) >> 16);
}

#define FENCE() asm volatile("" ::: "memory")
__device__ __forceinline__ void barx() { FENCE(); __builtin_amdgcn_s_barrier(); FENCE(); }

// ---------------- convert x (f32 -> bf16, zero pad rows) ----------------
__global__ __launch_bounds__(256) void convert_x_k(const float* __restrict__ x, u16* __restrict__ xb) {
  const size_t g = ((size_t)blockIdx.x * 256 + threadIdx.x) * 4;
  if (g >= (size_t)NPAD * KDIM) return;
  ushort4 o;
  if (g < (size_t)NODES * KDIM) {
    const float4 v = *(const float4*)(x + g);
    o.x = f2bf(v.x); o.y = f2bf(v.y); o.z = f2bf(v.z); o.w = f2bf(v.w);
  } else { o.x = o.y = o.z = o.w = 0; }
  *(ushort4*)(xb + g) = o;
}

// ---------------- weight prep (LDS-tiled transpose) ----------------
// MODE 0: WT[n][k] = [W | skip][k][n], n<1536
// MODE 1: WT[n][k] = n<768 ? W[k][n] : (n<896 ? mean_h skip[k][h*128+(n-768)] : 0), n<1024
template <int MODE>
__global__ __launch_bounds__(256) void prep_wcat_k(const float* __restrict__ W, const float* __restrict__ SK,
                                                   u16* __restrict__ WT) {
  __shared__ u16 tile[32][33];
  const int n0 = blockIdx.x * 32, k0 = blockIdx.y * 32;
  const int tx = threadIdx.x & 31, ty = threadIdx.x >> 5;  // 32 x 8
#pragma unroll
  for (int r = 0; r < 32; r += 8) {
    const int k = k0 + ty + r, n = n0 + tx;
    float v;
    if (n < HF) {
      v = W[(size_t)k * HF + n];
    } else if (MODE == 0) {
      v = SK[(size_t)k * HF + (n - HF)];
    } else if (n < 896) {
      const int f = n - HF;
      v = 0.f;
#pragma unroll
      for (int h = 0; h < 6; ++h) v += SK[(size_t)k * HF + h * FOUT + f];
      v *= (1.0f / 6.0f);
    } else {
      v = 0.f;
    }
    tile[ty + r][tx] = f2bf(v);
  }
  __syncthreads();
#pragma unroll
  for (int r = 0; r < 32; r += 8) {
    const int n = n0 + ty + r, k = k0 + tx;
    WT[(size_t)n * KDIM + k] = tile[tx][ty + r];
  }
}

// ---------------- CSR build ----------------
__global__ __launch_bounds__(256) void hist_k(const int* __restrict__ tgt, int* __restrict__ deg) {
  const int e = blockIdx.x * 256 + threadIdx.x;
  if (e < EDGES) atomicAdd(&deg[tgt[e]], 1);
}

__global__ __launch_bounds__(1024) void scan_k(int* __restrict__ degcur, int* __restrict__ rp) {
  __shared__ int buf[1024];
  __shared__ int carry;
  const int tid = threadIdx.x;
  if (tid == 0) carry = 0;
  __syncthreads();
  for (int base = 0; base < NODES; base += 1024) {
    const int i = base + tid;
    const int v = (i < NODES) ? degcur[i] : 0;
    buf[tid] = v; __syncthreads();
    for (int off = 1; off < 1024; off <<= 1) {
      const int t2 = (tid >= off) ? buf[tid - off] : 0;
      __syncthreads();
      buf[tid] += t2;
      __syncthreads();
    }
    const int excl = buf[tid] - v + carry;
    if (i < NODES) { rp[i] = excl; degcur[i] = excl; }
    __syncthreads();
    if (tid == 1023) carry += buf[1023];
    __syncthreads();
  }
  if (tid == 0) rp[NODES] = carry;
}

__global__ __launch_bounds__(256) void scatter_k(const int* __restrict__ srcv, const int* __restrict__ tgt,
                                                 int* __restrict__ cur, int* __restrict__ esrc) {
  const int e = blockIdx.x * 256 + threadIdx.x;
  if (e < EDGES) {
    const int t = tgt[e];
    const int pos = atomicAdd(&cur[t], 1);
    esrc[pos] = srcv[e];
  }
}

// ---------------- per-target softmax: alpha = exp(sc - max); denom deferred ----------------
__global__ __launch_bounds__(256) void attn_k(const int* __restrict__ rp, const int* __restrict__ esrc,
                                              const float* __restrict__ ss, const float* __restrict__ stg,
                                              float* __restrict__ alp, float* __restrict__ invd) {
  const int t = blockIdx.x * 256 + threadIdx.x;
  if (t >= NODES) return;
  const int b = rp[t], e = rp[t + 1];
  float sth[6], m[6], d[6];
#pragma unroll
  for (int h = 0; h < 6; ++h) { sth[h] = stg[t * 6 + h]; m[h] = -1e30f; d[h] = 0.f; }
  for (int j = b; j < e; ++j) {
    const int s = esrc[j];
#pragma unroll
    for (int h = 0; h < 6; ++h) {
      float sc = ss[s * 6 + h] + sth[h];
      sc = sc > 0.f ? sc : 0.2f * sc;
      m[h] = fmaxf(m[h], sc);
    }
  }
  for (int j = b; j < e; ++j) {
    const int s = esrc[j];
#pragma unroll
    for (int h = 0; h < 6; ++h) {
      float sc = ss[s * 6 + h] + sth[h];
      sc = sc > 0.f ? sc : 0.2f * sc;
      const float ev = expf(sc - m[h]);
      d[h] += ev;
      alp[(size_t)j * 6 + h] = ev;
    }
  }
#pragma unroll
  for (int h = 0; h < 6; ++h) invd[t * 6 + h] = 1.f / (d[h] + 1e-16f);
}

// ---------------- 256x256 8-phase bf16 MFMA GEMM + fused attention-score epilogue ----------------
// C[NPAD x ncat] = A[NPAD x 768] * BT^T  (BT is [ncat x 768] row-major); ncat = nbx*256
// 512 threads = 8 waves (2M x 4N), per-wave output 128x64. BK=64, 12 K-tiles.
// LDS: A/B each 2dbuf x 2half x (128x64 bf16) = 64 KiB  -> 128 KiB total.
// A-half h = rows {g*128 + h*64 + s : g<2}        (local rho = g*64 + s)       read in phase mh==h
// B-half h = cols {wn*64 + h*32 + s : wn<4}       (local rho = wn*32 + s)      read in phase nh==h
// XOR swizzle byte ^= (row&7)<<4 : linear LDS dest (global_load_lds) + inverse-swizzled global src + swizzled ds_read.
// Counted vmcnt(6): 3 half-tiles in flight. Stage order per tile t:
//   phi0 -> (t+1)B1, phi1 -> (t+2)A0, phi2 -> (t+2)B0, phi3 -> (t+2)A1
// At each phi3's vmcnt(6) the 8 oldest outstanding = all of tile t+1. Last staged tile drains with vmcnt(0).
__global__ __launch_bounds__(512, 2) void gemm_k(const u16* __restrict__ A, const u16* __restrict__ BT,
                                                 u16* __restrict__ C,
                                                 const float* __restrict__ a_src, const float* __restrict__ a_tgt,
                                                 float* __restrict__ ss, float* __restrict__ stg,
                                                 int nbx, int ncat) {
  __shared__ u16 Al[2][2][128 * 64];
  __shared__ u16 Bl[2][2][128 * 64];
  float* sp = (float*)&Al[0][0][0];  // score scratch, aliases dead A region after the K loop

  const int tid = threadIdx.x;
  const int lane = tid & 63;
  const int w = tid >> 6;
  const int wm = w >> 2, wn = w & 3;
  const int r16 = lane & 15, g4 = lane >> 4;

  // XCD-chunked bijective swizzle (m204)
  const int gd = gridDim.x;
  const int q = gd >> 3, rr = gd & 7;
  const int orig = blockIdx.x;
  const int xcd = orig & 7, idx = orig >> 3;
  const int wg = (xcd < rr ? xcd * (q + 1) : rr * (q + 1) + (xcd - rr) * q) + idx;
  const int bx = wg % nbx, by = wg / nbx;

  const size_t rowBase = (size_t)by * 256;
  const int colBase = bx * 256;

  // stage one half-tile (128 local rows x 64 k bf16 = 16 KB = 2 issues/thread)
  auto stage = [&](int tile, int kind) {  // kind: 0=A0 1=A1 2=B0 3=B1
    const int h = kind & 1;
    const int bufS = tile & 1;
    const u16* srcBase = (kind < 2) ? A : BT;
    const size_t rcBase = (kind < 2) ? rowBase : (size_t)colBase;
    u16* slot = (kind < 2) ? &Al[bufS][h][0] : &Bl[bufS][h][0];
#pragma unroll
    for (int qq = 0; qq < 2; ++qq) {
      const int wb = (tid + qq * 512) * 16;  // linear byte in half-tile
      const int rho = wb >> 7;
      const int colb = (wb & 127) ^ ((rho & 7) << 4);
      const size_t grow = (kind < 2)
          ? rcBase + (size_t)((rho >> 6) << 7) + h * 64 + (rho & 63)
          : rcBase + (size_t)((rho >> 5) << 6) + h * 32 + (rho & 31);
      const char* gp = (const char*)srcBase + grow * (KDIM * 2) + tile * 128 + colb;
      u16* lp = slot + ((qq * 8192 + w * 1024) >> 1);
      __builtin_amdgcn_global_load_lds((const __attribute__((address_space(1))) void*)gp,
                                       (__attribute__((address_space(3))) void*)lp, 16, 0, 0);
    }
  };

  auto ldA = [&](int bufc, int mh, int ii, int kk) -> bf16x8 {
    const int rho = wm * 64 + ii * 16 + r16;
    const int byte = rho * 128 + ((kk * 64 + g4 * 16) ^ ((r16 & 7) << 4));
    return *(const bf16x8*)((const char*)&Al[bufc][mh][0] + byte);
  };
  auto ldB = [&](int bufc, int nh, int jj, int kk) -> bf16x8 {
    const int rho = wn * 32 + jj * 16 + r16;
    const int byte = rho * 128 + ((kk * 64 + g4 * 16) ^ ((r16 & 7) << 4));
    return *(const bf16x8*)((const char*)&Bl[bufc][nh][0] + byte);
  };

  f32x4 acc[8][4];
#pragma unroll
  for (int i = 0; i < 8; ++i)
#pragma unroll
    for (int j = 0; j < 4; ++j) acc[i][j] = f32x4{0.f, 0.f, 0.f, 0.f};

  // prologue: t0 all four halves, then t1 A0,B0,A1 (t1 B1 staged at t0 phi0)
  stage(0, 0); stage(0, 1); stage(0, 2); stage(0, 3);
  stage(1, 0); stage(1, 2); stage(1, 1);
  asm volatile("s_waitcnt vmcnt(6)" ::: "memory");
  barx();

  bf16x8 a[4][2], b0[2][2], b1[2][2];

  for (int t = 0; t < NT; ++t) {
    const int buf = t & 1;
    // ---- phase 0: quadrant (mh0, nh0) ----
#pragma unroll
    for (int ii = 0; ii < 4; ++ii)
#pragma unroll
      for (int kk = 0; kk < 2; ++kk) a[ii][kk] = ldA(buf, 0, ii, kk);
#pragma unroll
    for (int jj = 0; jj < 2; ++jj)
#pragma unroll
      for (int kk = 0; kk < 2; ++kk) b0[jj][kk] = ldB(buf, 0, jj, kk);
    if (t + 1 < NT) stage(t + 1, 3);
    barx();
    __builtin_amdgcn_s_setprio(1);
#pragma unroll
    for (int ii = 0; ii < 4; ++ii)
#pragma unroll
      for (int jj = 0; jj < 2; ++jj) {
        acc[ii][jj] = __builtin_amdgcn_mfma_f32_16x16x32_bf16(a[ii][0], b0[jj][0], acc[ii][jj], 0, 0, 0);
        acc[ii][jj] = __builtin_amdgcn_mfma_f32_16x16x32_bf16(a[ii][1], b0[jj][1], acc[ii][jj], 0, 0, 0);
      }
    __builtin_amdgcn_s_setprio(0);
    __builtin_amdgcn_sched_barrier(0);
    barx();
    // ---- phase 1: quadrant (mh0, nh1) ----
#pragma unroll
    for (int jj = 0; jj < 2; ++jj)
#pragma unroll
      for (int kk = 0; kk < 2; ++kk) b1[jj][kk] = ldB(buf, 1, jj, kk);
    if (t + 2 < NT) stage(t + 2, 0);
    barx();
    __builtin_amdgcn_s_setprio(1);
#pragma unroll
    for (int ii = 0; ii < 4; ++ii)
#pragma unroll
      for (int jj = 0; jj < 2; ++jj) {
        acc[ii][2 + jj] = __builtin_amdgcn_mfma_f32_16x16x32_bf16(a[ii][0], b1[jj][0], acc[ii][2 + jj], 0, 0, 0);
        acc[ii][2 + jj] = __builtin_amdgcn_mfma_f32_16x16x32_bf16(a[ii][1], b1[jj][1], acc[ii][2 + jj], 0, 0, 0);
      }
    __builtin_amdgcn_s_setprio(0);
    __builtin_amdgcn_sched_barrier(0);
    barx();
    // ---- phase 2: quadrant (mh1, nh1) ----
#pragma unroll
    for (int ii = 0; ii < 4; ++ii)
#pragma unroll
      for (int kk = 0; kk < 2; ++kk) a[ii][kk] = ldA(buf, 1, ii, kk);
    if (t + 2 < NT) stage(t + 2, 2);
    barx();
    __builtin_amdgcn_s_setprio(1);
#pragma unroll
    for (int ii = 0; ii < 4; ++ii)
#pragma unroll
      for (int jj = 0; jj < 2; ++jj) {
        acc[4 + ii][2 + jj] = __builtin_amdgcn_mfma_f32_16x16x32_bf16(a[ii][0], b1[jj][0], acc[4 + ii][2 + jj], 0, 0, 0);
        acc[4 + ii][2 + jj] = __builtin_amdgcn_mfma_f32_16x16x32_bf16(a[ii][1], b1[jj][1], acc[4 + ii][2 + jj], 0, 0, 0);
      }
    __builtin_amdgcn_s_setprio(0);
    __builtin_amdgcn_sched_barrier(0);
    barx();
    // ---- phase 3: quadrant (mh1, nh0), b0 cached from phase 0 ----
    if (t + 2 < NT) {
      stage(t + 2, 1);
      asm volatile("s_waitcnt vmcnt(6)" ::: "memory");
    } else {
      asm volatile("s_waitcnt vmcnt(0)" ::: "memory");  // epilogue: fully drain last staged tile
    }
    barx();
    __builtin_amdgcn_s_setprio(1);
#pragma unroll
    for (int ii = 0; ii < 4; ++ii)
#pragma unroll
      for (int jj = 0; jj < 2; ++jj) {
        acc[4 + ii][jj] = __builtin_amdgcn_mfma_f32_16x16x32_bf16(a[ii][0], b0[jj][0], acc[4 + ii][jj], 0, 0, 0);
        acc[4 + ii][jj] = __builtin_amdgcn_mfma_f32_16x16x32_bf16(a[ii][1], b0[jj][1], acc[4 + ii][jj], 0, 0, 0);
      }
    __builtin_amdgcn_s_setprio(0);
    __builtin_amdgcn_sched_barrier(0);
    barx();
  }

  // ---- C write ----
#pragma unroll
  for (int i = 0; i < 8; ++i) {
    const size_t row0 = rowBase + wm * 128 + (i >> 2) * 64 + (i & 3) * 16 + g4 * 4;
#pragma unroll
    for (int j = 0; j < 4; ++j) {
      const int col = colBase + wn * 64 + (j >> 1) * 32 + (j & 1) * 16 + r16;
#pragma unroll
      for (int r = 0; r < 4; ++r)
        C[(row0 + r) * ncat + col] = f2bf(acc[i][j][r]);
    }
  }

  // ---- fused attention-score epilogue: block covers heads 2bx, 2bx+1 (proj iff bx<3) ----
  if (bx < 3) {
    const int hh = 2 * bx + (wn >> 1);
#pragma unroll
    for (int pass = 0; pass < 2; ++pass) {
      const float* av = (pass == 0) ? a_src : a_tgt;
      float a4[4];
#pragma unroll
      for (int j = 0; j < 4; ++j) {
        const int f = (wn & 1) * 64 + (j >> 1) * 32 + (j & 1) * 16 + r16;
        a4[j] = av[hh * FOUT + f];
      }
#pragma unroll
      for (int i = 0; i < 8; ++i) {
#pragma unroll
        for (int r = 0; r < 4; ++r) {
          float p = 0.f;
#pragma unroll
          for (int j = 0; j < 4; ++j) p += acc[i][j][r] * a4[j];
#pragma unroll
          for (int off = 1; off < 16; off <<= 1) p += __shfl_xor(p, off, 64);
          if (r16 == 0) sp[(pass * 8 + w) * 128 + i * 16 + g4 * 4 + r] = p;
        }
      }
    }
    barx();
    // combine: 512 threads -> (row 0..255) x (head-sel 0..1)
    {
      const int row = tid & 255, hsel = tid >> 8;
      const int wmr = row >> 7, lr = row & 127;
      const size_t grow = rowBase + row;
      if (grow < NODES) {
        const int wa = wmr * 4 + hsel * 2;
        const float vS = sp[(0 * 8 + wa) * 128 + lr] + sp[(0 * 8 + wa + 1) * 128 + lr];
        const float vT = sp[(1 * 8 + wa) * 128 + lr] + sp[(1 * 8 + wa + 1) * 128 + lr];
        const int head = 2 * bx + hsel;
        ss[grow * 6 + head] = vS;
        stg[grow * 6 + head] = vT;
      }
    }
  }
}

// ---------------- aggregation: one wave per target node, vectorized, deferred denom ----------------
// lane covers cols {lane*4 + 256k + c : k<3, c<4}; head(col) = (lane>>5) + 2k
template <int MODE>
__global__ __launch_bounds__(256) void aggregate_k(const u16* __restrict__ Cb, const int* __restrict__ rp,
                                                   const int* __restrict__ esrc, const float* __restrict__ alp,
                                                   const float* __restrict__ invd, const float* __restrict__ bias,
                                                   u16* __restrict__ xnext, float* __restrict__ outf) {
  constexpr int ncat = (MODE == 0) ? 1536 : 1024;
  const int t = blockIdx.x * 4 + (threadIdx.x >> 6);
  const int lane = threadIdx.x & 63;
  if (t >= NODES) return;
  const int l4 = lane * 4;
  const int h0 = lane >> 5;
  float macc[3][4];
#pragma unroll
  for (int k = 0; k < 3; ++k)
#pragma unroll
    for (int c = 0; c < 4; ++c) macc[k][c] = 0.f;

  const int b = rp[t], e = rp[t + 1];
  int j = b;
  for (; j + 1 < e; j += 2) {
    const int s0 = esrc[j], s1 = esrc[j + 1];
    const float2 p0 = *(const float2*)(alp + (size_t)j * 6);
    const float2 p1 = *(const float2*)(alp + (size_t)j * 6 + 2);
    const float2 p2 = *(const float2*)(alp + (size_t)j * 6 + 4);
    const float2 q0 = *(const float2*)(alp + (size_t)(j + 1) * 6);
    const float2 q1 = *(const float2*)(alp + (size_t)(j + 1) * 6 + 2);
    const float2 q2 = *(const float2*)(alp + (size_t)(j + 1) * 6 + 4);
    const float a0[6] = {p0.x, p0.y, p1.x, p1.y, p2.x, p2.y};
    const float a1[6] = {q0.x, q0.y, q1.x, q1.y, q2.x, q2.y};
    const u16* pr0 = Cb + (size_t)s0 * ncat;
    const u16* pr1 = Cb + (size_t)s1 * ncat;
#pragma unroll
    for (int k = 0; k < 3; ++k) {
      const ushort4 v0 = *(const ushort4*)(pr0 + l4 + 256 * k);
      const ushort4 v1 = *(const ushort4*)(pr1 + l4 + 256 * k);
      const float aa0 = a0[h0 + 2 * k], aa1 = a1[h0 + 2 * k];
      macc[k][0] += aa0 * bf2f(v0.x) + aa1 * bf2f(v1.x);
      macc[k][1] += aa0 * bf2f(v0.y) + aa1 * bf2f(v1.y);
      macc[k][2] += aa0 * bf2f(v0.z) + aa1 * bf2f(v1.z);
      macc[k][3] += aa0 * bf2f(v0.w) + aa1 * bf2f(v1.w);
    }
  }
  if (j < e) {
    const int s0 = esrc[j];
    const float2 p0 = *(const float2*)(alp + (size_t)j * 6);
    const float2 p1 = *(const float2*)(alp + (size_t)j * 6 + 2);
    const float2 p2 = *(const float2*)(alp + (size_t)j * 6 + 4);
    const float a0[6] = {p0.x, p0.y, p1.x, p1.y, p2.x, p2.y};
    const u16* pr0 = Cb + (size_t)s0 * ncat;
#pragma unroll
    for (int k = 0; k < 3; ++k) {
      const ushort4 v0 = *(const ushort4*)(pr0 + l4 + 256 * k);
      const float aa0 = a0[h0 + 2 * k];
      macc[k][0] += aa0 * bf2f(v0.x);
      macc[k][1] += aa0 * bf2f(v0.y);
      macc[k][2] += aa0 * bf2f(v0.z);
      macc[k][3] += aa0 * bf2f(v0.w);
    }
  }

  float inv[3];
#pragma unroll
  for (int k = 0; k < 3; ++k) inv[k] = invd[t * 6 + h0 + 2 * k];

  if (MODE == 0) {
    const u16* sk = Cb + (size_t)t * ncat + HF;
#pragma unroll
    for (int k = 0; k < 3; ++k) {
      const ushort4 s4 = *(const ushort4*)(sk + l4 + 256 * k);
      ushort4 o;
      float v0 = macc[k][0] * inv[k] + bf2f(s4.x) + bias[l4 + 256 * k];
      float v1 = macc[k][1] * inv[k] + bf2f(s4.y) + bias[l4 + 256 * k + 1];
      float v2 = macc[k][2] * inv[k] + bf2f(s4.z) + bias[l4 + 256 * k + 2];
      float v3 = macc[k][3] * inv[k] + bf2f(s4.w) + bias[l4 + 256 * k + 3];
      o.x = f2bf(v0 > 0.f ? v0 : expm1f(v0));
      o.y = f2bf(v1 > 0.f ? v1 : expm1f(v1));
      o.z = f2bf(v2 > 0.f ? v2 : expm1f(v2));
      o.w = f2bf(v3 > 0.f ? v3 : expm1f(v3));
      *(ushort4*)(xnext + (size_t)t * HF + l4 + 256 * k) = o;
    }
  } else {
    float4 o;
    float* op = &o.x;
#pragma unroll
    for (int c = 0; c < 4; ++c) {
      const float s3 = macc[0][c] * inv[0] + macc[1][c] * inv[1] + macc[2][c] * inv[2];
      const float tot = s3 + __shfl_xor(s3, 32, 64);
      op[c] = tot * (1.0f / 6.0f);
    }
    if (lane < 32) {
      const int f = lane * 4;
      const ushort4 s4 = *(const ushort4*)(Cb + (size_t)t * ncat + HF + f);
      o.x += bf2f(s4.x) + bias[f];
      o.y += bf2f(s4.y) + bias[f + 1];
      o.z += bf2f(s4.z) + bias[f + 2];
      o.w += bf2f(s4.w) + bias[f + 3];
      *(float4*)(outf + (size_t)t * FOUT + f) = o;
    }
  }
}

// ---------------- workspace layout ----------------
#define OFF_XBF 0ull
#define OFF_CB  92405760ull
#define OFF_WT  277217280ull   // invd aliases this region between attn and aggregate
#define OFF_SS  279576576ull
#define OFF_ST  281016576ull
#define OFF_ALP 282456576ull
#define OFF_RP  288216576ull
#define OFF_CUR 288456640ull
#define OFF_ESR 288696640ull

extern "C" void kernel_launch(void* const* d_in, const int* in_sizes, int n_in,
                              void* d_out, int out_size, void* d_ws, size_t ws_size,
                              hipStream_t stream) {
  const float* x = (const float*)d_in[0];
  const int ei = (in_sizes[1] == 2 * EDGES) ? 1 : 16;
  const int base = (ei == 1) ? 2 : 1;
  const float *W[3], *AS[3], *AT[3], *SK[3], *B[3];
  for (int l = 0; l < 3; ++l) {
    W[l]  = (const float*)d_in[base + 5 * l + 0];
    AS[l] = (const float*)d_in[base + 5 * l + 1];
    AT[l] = (const float*)d_in[base + 5 * l + 2];
    SK[l] = (const float*)d_in[base + 5 * l + 3];
    B[l]  = (const float*)d_in[base + 5 * l + 4];
  }
  const int* edges = (const int*)d_in[ei];
  const int* srcv = edges;
  const int* tgtv = edges + EDGES;
  float* out = (float*)d_out;

  char* ws = (char*)d_ws;
  u16* xbf = (u16*)(ws + OFF_XBF);
  u16* Cb  = (u16*)(ws + OFF_CB);
  u16* WT  = (u16*)(ws + OFF_WT);
  float* invd = (float*)(ws + OFF_WT);   // aliases WT: live only between attn_k and aggregate_k
  float* ss  = (float*)(ws + OFF_SS);
  float* stg = (float*)(ws + OFF_ST);
  float* alp = (float*)(ws + OFF_ALP);
  int* rp  = (int*)(ws + OFF_RP);
  int* cur = (int*)(ws + OFF_CUR);
  int* esr = (int*)(ws + OFF_ESR);

  // CSR build
  hipMemsetAsync(cur, 0, NODES * sizeof(int), stream);
  hist_k<<<(EDGES + 255) / 256, 256, 0, stream>>>(tgtv, cur);
  scan_k<<<1, 1024, 0, stream>>>(cur, rp);
  scatter_k<<<(EDGES + 255) / 256, 256, 0, stream>>>(srcv, tgtv, cur, esr);

  convert_x_k<<<45120, 256, 0, stream>>>(x, xbf);

  for (int l = 0; l < 3; ++l) {
    const int nbx = (l < 2) ? 6 : 4;      // 256-col blocks
    const int ncat = nbx * 256;
    if (l < 2)
      prep_wcat_k<0><<<dim3(48, 24), 256, 0, stream>>>(W[l], SK[l], WT);
    else
      prep_wcat_k<1><<<dim3(32, 24), 256, 0, stream>>>(W[l], SK[l], WT);
    gemm_k<<<nbx * 235, 512, 0, stream>>>(xbf, WT, Cb, AS[l], AT[l], ss, stg, nbx, ncat);
    attn_k<<<(NODES + 255) / 256, 256, 0, stream>>>(rp, esr, ss, stg, alp, invd);
    if (l < 2)
      aggregate_k<0><<<15000, 256, 0, stream>>>(Cb, rp, esr, alp, invd, B[l], xbf, nullptr);
    else
      aggregate_k<1><<<15000, 256, 0, stream>>>(Cb, rp, esr, alp, invd, B[l], nullptr, out);
  }
}